// Round 8
// baseline (241.246 us; speedup 1.0000x reference)
//
#include <hip/hip_runtime.h>
#include <hip/hip_bf16.h>

// QLinear: per-row absmax int8 quant -> int8 GEMM (MFMA) -> fused dequant.
// M=8192, K=4096, N=4096 (derived from in_sizes at launch).

using int32x4 = __attribute__((ext_vector_type(4))) int;

#define QMAXF 127.0f

// ---------------------------------------------------------------------------
// Kernel 0: weight repack (int32-marshalled int8 -> packed int8).
// ---------------------------------------------------------------------------
__global__ __launch_bounds__(256) void repack_weights(
    const int* __restrict__ w, signed char* __restrict__ w8, int total)
{
    bool is32 = true;
#pragma unroll
    for (int i = 0; i < 16; ++i) {
        int v = w[i];
        is32 = is32 && (v >= -127 && v <= 127);
    }

    const int t = blockIdx.x * blockDim.x + threadIdx.x;
    const int nth = gridDim.x * blockDim.x;
    const int chunks = total / 16;

    if (is32) {
        for (int c = t; c < chunks; c += nth) {
            const int32x4* src = reinterpret_cast<const int32x4*>(w + (size_t)c * 16);
            int32x4 a0 = src[0], a1 = src[1], a2 = src[2], a3 = src[3];
            int32x4 o;
            o[0] = (a0[0] & 0xff) | ((a0[1] & 0xff) << 8) | ((a0[2] & 0xff) << 16) | ((a0[3] & 0xff) << 24);
            o[1] = (a1[0] & 0xff) | ((a1[1] & 0xff) << 8) | ((a1[2] & 0xff) << 16) | ((a1[3] & 0xff) << 24);
            o[2] = (a2[0] & 0xff) | ((a2[1] & 0xff) << 8) | ((a2[2] & 0xff) << 16) | ((a2[3] & 0xff) << 24);
            o[3] = (a3[0] & 0xff) | ((a3[1] & 0xff) << 8) | ((a3[2] & 0xff) << 16) | ((a3[3] & 0xff) << 24);
            reinterpret_cast<int32x4*>(w8)[c] = o;
        }
    } else {
        const int32x4* src = reinterpret_cast<const int32x4*>(w);
        int32x4* dst = reinterpret_cast<int32x4*>(w8);
        for (int c = t; c < chunks; c += nth) dst[c] = src[c];
    }
}

// ---------------------------------------------------------------------------
// Kernel 1: per-row absmax quantization. One block (256 thr) per row, K=4096.
// ---------------------------------------------------------------------------
__global__ __launch_bounds__(256) void quant_rows(
    const float* __restrict__ x, signed char* __restrict__ q,
    float* __restrict__ scale, int K)
{
    const int row = blockIdx.x;
    const int t = threadIdx.x;
    const float4* xr = reinterpret_cast<const float4*>(x + (size_t)row * K);

    float4 v[4];
    float m = 0.f;
#pragma unroll
    for (int i = 0; i < 4; ++i) {
        v[i] = xr[t + i * 256];
        m = fmaxf(m, fmaxf(fmaxf(fabsf(v[i].x), fabsf(v[i].y)),
                           fmaxf(fabsf(v[i].z), fabsf(v[i].w))));
    }
#pragma unroll
    for (int off = 32; off >= 1; off >>= 1)
        m = fmaxf(m, __shfl_xor(m, off, 64));
    __shared__ float wmax[4];
    const int wave = t >> 6;
    if ((t & 63) == 0) wmax[wave] = m;
    __syncthreads();
    m = fmaxf(fmaxf(wmax[0], wmax[1]), fmaxf(wmax[2], wmax[3]));

    const float s   = m / QMAXF;
    const float inv = (m > 0.f) ? (QMAXF / m) : 0.f;
    if (t == 0) scale[row] = s;

    int* qr = reinterpret_cast<int*>(q + (size_t)row * K);
#pragma unroll
    for (int i = 0; i < 4; ++i) {
        const float* f = reinterpret_cast<const float*>(&v[i]);
        unsigned int packed = 0;
#pragma unroll
        for (int j = 0; j < 4; ++j) {
            int qi = __float2int_rn(f[j] * inv);
            qi = qi > 127 ? 127 : (qi < -127 ? -127 : qi);
            packed |= ((unsigned int)(qi & 0xff)) << (8 * j);
        }
        qr[t + i * 256] = (int)packed;
    }
}

// ---------------------------------------------------------------------------
// Kernel 2: int8 GEMM, 256x128 tile, 4 waves (2Mx2N), K-step = 64 bytes,
// NBUF=3 x 24 KB = 72 KiB LDS -> TWO independent blocks per CU (the m114
// cross-block overlap mechanism: one block's DS burst/barrier overlaps the
// other block's MFMA cluster; no intra-block schedule can do this at 1
// block/CU lockstep -- rounds 4/5/7 all measured identical 170 us).
//
// Fragment-order LDS (zero bank conflicts): 1 KB frag-tile fi holds the MFMA
// operand for rows [fi*16,fi*16+16) x 64 k-bytes, lane-linear; per-lane
// global address is row fi*16+(l&15), kcol (l>>4)*16, so every ds_read_b128
// at base + lane*16 is fully linear.
//
// Ledger (steady iter tt, buffers tt%3):
//  - stage(tt+2) -> buf (tt+2)%3; own outstanding after issue = 12
//    (tiles tt+1, tt+2); VM6 retires the 6 oldest = tile tt+1; fenced
//    barrier promotes to all-waves -> iter tt+1 may read buf (tt+1)%3.
//  - WAR: stage(tt+2) rewrites buf (tt-1)%3. Iter tt-1's ds_reads of that
//    buffer are register-consumed by its MFMAs (hw lgkm dep), which the
//    sched_barrier-fenced barrier pins before this iter's stage. Safe.
//  - Raw s_barrier is NOT a compiler fence: every barrier is two-side
//    fenced (sched_barrier(0) + asm memory clobber) -- round 6's race fix.
//
// Epilogue: per-wave-private LDS transpose (272 B row stride, 2-way banks)
// turns the C-write into global_store_dwordx4 with 256 B coalesced runs.
// ---------------------------------------------------------------------------
#define BM 256
#define BN 128
#define BKB 64
#define NBUF 3
#define BUFSZ 24576          // 16 KB A + 8 KB B

__device__ __forceinline__ void async_copy16(const void* g, void* lds) {
    __builtin_amdgcn_global_load_lds(
        (const __attribute__((address_space(1))) void*)g,
        (__attribute__((address_space(3))) void*)lds, 16, 0, 0);
}

// fenced barrier: no memory op may move across, in either direction
#define BARF do {                                         \
    __builtin_amdgcn_sched_barrier(0);                    \
    asm volatile("" ::: "memory");                        \
    __builtin_amdgcn_s_barrier();                         \
    asm volatile("" ::: "memory");                        \
    __builtin_amdgcn_sched_barrier(0);                    \
} while (0)

#define VM6   asm volatile("s_waitcnt vmcnt(6)" ::: "memory")
#define VM0   asm volatile("s_waitcnt vmcnt(0)" ::: "memory")

__global__ __launch_bounds__(256, 2) void gemm_i8_dequant_2b(
    const signed char* __restrict__ A,   // [M,K] qinp
    const signed char* __restrict__ B,   // [N,K] qweight (packed int8)
    const float* __restrict__ a_scale,   // [M]
    const float* __restrict__ wparams,   // [N]
    const float* __restrict__ bias,      // [N]
    float* __restrict__ out,             // [M,N]
    int M, int N, int K)
{
    __shared__ __align__(16) signed char lds[NBUF * BUFSZ];   // 72 KiB

    const int t    = threadIdx.x;
    const int lane = t & 63;
    const int wave = t >> 6;           // 0..3
    const int wr   = wave >> 1;        // 0..1 (M half: 128 rows)
    const int wc   = wave & 1;         // 0..1 (N half: 64 cols)

    // T1: XCD-aware bijective swizzle (nwg = 1024, % 8 == 0)
    const int nwg = gridDim.x;
    const int cpx = nwg >> 3;
    const int swz = (blockIdx.x & 7) * cpx + (blockIdx.x >> 3);
    const int nbx = N / BN;            // 32
    const int rowBase = (swz / nbx) * BM;
    const int colBase = (swz % nbx) * BN;

    const int r15 = lane & 15;
    const int ksl = lane >> 4;

    int32x4 acc[8][4] = {};
    const int NT = K / BKB;            // 64

    // per-thread global staging addresses: A-frags j*4+wave (j=0..3),
    // B-frags j*4+wave (j=0..1)
    const signed char* gA[4];
#pragma unroll
    for (int j = 0; j < 4; ++j)
        gA[j] = A + (size_t)(rowBase + (j * 4 + wave) * 16 + r15) * K + ksl * 16;
    const signed char* gB[2];
#pragma unroll
    for (int j = 0; j < 2; ++j)
        gB[j] = B + (size_t)(colBase + (j * 4 + wave) * 16 + r15) * K + ksl * 16;

    auto stage = [&](int tile, signed char* buf) {
        const size_t kt = (size_t)tile * BKB;
#pragma unroll
        for (int j = 0; j < 4; ++j)
            async_copy16(gA[j] + kt, buf + (j * 4 + wave) * 1024);
#pragma unroll
        for (int j = 0; j < 2; ++j)
            async_copy16(gB[j] + kt, buf + 16384 + (j * 4 + wave) * 1024);
    };

    auto compute = [&](const signed char* buf) {
        const signed char* Ab = buf + (wr * 8) * 1024 + lane * 16;
        const signed char* Bb = buf + 16384 + (wc * 4) * 1024 + lane * 16;
        int32x4 af[8], bf[4];
#pragma unroll
        for (int nn = 0; nn < 4; ++nn)
            bf[nn] = *reinterpret_cast<const int32x4*>(Bb + nn * 1024);
#pragma unroll
        for (int mm = 0; mm < 8; ++mm)
            af[mm] = *reinterpret_cast<const int32x4*>(Ab + mm * 1024);
        __builtin_amdgcn_s_setprio(1);
#pragma unroll
        for (int mm = 0; mm < 8; ++mm)
#pragma unroll
            for (int nn = 0; nn < 4; ++nn)
                acc[mm][nn] = __builtin_amdgcn_mfma_i32_16x16x64_i8(
                    af[mm], bf[nn], acc[mm][nn], 0, 0, 0);
        __builtin_amdgcn_s_setprio(0);
    };

    // ---- prologue: stage tiles 0,1 (12 loads/thread) ----
    stage(0, lds);
    stage(1, lds + BUFSZ);
    VM6;                               // own tile-0 loads landed
    BARF;                              // all waves' tile-0 loads landed

    // ---- steady: tt = 0 .. NT-3 ----
    int brd = 0;                       // read buf = tt % 3
    for (int tt = 0; tt < NT - 2; ++tt) {
        const int bw = brd == 0 ? 2 : brd - 1;   // (tt+2) % 3
        stage(tt + 2, lds + bw * BUFSZ);
        compute(lds + brd * BUFSZ);
        VM6;                           // tile tt+1 landed
        BARF;
        brd = brd == 2 ? 0 : brd + 1;
    }
    // ---- tails: tiles NT-2, NT-1 ----
    compute(lds + brd * BUFSZ);        // tile NT-2
    VM0;                               // tile NT-1 landed
    BARF;
    brd = brd == 2 ? 0 : brd + 1;
    compute(lds + brd * BUFSZ);        // tile NT-1
    BARF;                              // all reads retired before LDS reuse

    // ---- epilogue: dequant + bias, then coalesced write via per-wave LDS
    // transpose. C/D map: col=lane&15, row=(lane>>4)*4+r.
    // Region: 16 rows x 272 B (68 floats) per wave -> 2-way banks (free).
    signed char* ep = lds + wave * 4352;
    const int col = colBase + wc * 64 + r15;     // col for this lane's accs
    const float wp = wparams[col];
    const float bs = bias[col];
#pragma unroll
    for (int mm = 0; mm < 8; ++mm) {
        const int rb = rowBase + wr * 128 + mm * 16 + ksl * 4;
        float asc[4];
#pragma unroll
        for (int r = 0; r < 4; ++r) asc[r] = a_scale[rb + r];
#pragma unroll
        for (int nn = 0; nn < 4; ++nn) {
            const float wpn = wparams[colBase + wc * 64 + nn * 16 + r15];
            const float bsn = bias[colBase + wc * 64 + nn * 16 + r15];
#pragma unroll
            for (int r = 0; r < 4; ++r) {
                const float v = (float)acc[mm][nn][r] * asc[r] * wpn + bsn;
                *reinterpret_cast<float*>(
                    ep + (ksl * 4 + r) * 272 + (nn * 16 + r15) * 4) = v;
            }
        }
        // read back row-major, store 256 B runs (16 lanes x float4 per row)
#pragma unroll
        for (int it = 0; it < 4; ++it) {
            const int row16 = it * 4 + ksl;
            const float4 v = *reinterpret_cast<const float4*>(
                ep + row16 * 272 + r15 * 16);
            *reinterpret_cast<float4*>(
                &out[(size_t)(rowBase + wr * 128 + mm * 16 + row16) * N +
                     colBase + wc * 64 + r15 * 4]) = v;
        }
    }
    (void)wp; (void)bs;
}

// ---------------------------------------------------------------------------
extern "C" void kernel_launch(void* const* d_in, const int* in_sizes, int n_in,
                              void* d_out, int out_size, void* d_ws, size_t ws_size,
                              hipStream_t stream) {
    const float* inp     = (const float*)d_in[0];
    const int*   qw_raw  = (const int*)d_in[1];
    const float* wparams = (const float*)d_in[2];
    const float* bias    = (const float*)d_in[3];
    float*       out     = (float*)d_out;

    const int N = in_sizes[2];             // 4096
    const int K = in_sizes[1] / N;         // 4096
    const int M = in_sizes[0] / K;         // 8192

    // workspace: qinp [M*K B] | a_scale [M*4 B, 256-pad] | w8 [N*K B]
    signed char* qinp    = (signed char*)d_ws;
    float*       a_scale = (float*)((char*)d_ws + (size_t)M * K);
    size_t off_w8 = (size_t)M * K + (((size_t)M * sizeof(float) + 255) & ~(size_t)255);
    signed char* w8      = (signed char*)((char*)d_ws + off_w8);

    repack_weights<<<2048, 256, 0, stream>>>(qw_raw, w8, N * K);
    quant_rows<<<M, 256, 0, stream>>>(inp, qinp, a_scale, K);

    const int nwg = (M / BM) * (N / BN);   // 32*32 = 1024, %8 == 0
    gemm_i8_dequant_2b<<<nwg, 256, 0, stream>>>(
        qinp, w8, a_scale, wparams, bias, out, M, N, K);
}

// Round 9
// 203.522 us; speedup vs baseline: 1.1854x; 1.1854x over previous
//
#include <hip/hip_runtime.h>
#include <hip/hip_bf16.h>

// QLinear: per-row absmax int8 quant -> int8 GEMM (MFMA) -> fused dequant.
// M=8192, K=4096, N=4096 (derived from in_sizes at launch).

using int32x4 = __attribute__((ext_vector_type(4))) int;

#define QMAXF 127.0f

// ---------------------------------------------------------------------------
// Kernel 0: weight repack (int32-marshalled int8 -> packed int8).
// ---------------------------------------------------------------------------
__global__ __launch_bounds__(256) void repack_weights(
    const int* __restrict__ w, signed char* __restrict__ w8, int total)
{
    bool is32 = true;
#pragma unroll
    for (int i = 0; i < 16; ++i) {
        int v = w[i];
        is32 = is32 && (v >= -127 && v <= 127);
    }

    const int t = blockIdx.x * blockDim.x + threadIdx.x;
    const int nth = gridDim.x * blockDim.x;
    const int chunks = total / 16;

    if (is32) {
        for (int c = t; c < chunks; c += nth) {
            const int32x4* src = reinterpret_cast<const int32x4*>(w + (size_t)c * 16);
            int32x4 a0 = src[0], a1 = src[1], a2 = src[2], a3 = src[3];
            int32x4 o;
            o[0] = (a0[0] & 0xff) | ((a0[1] & 0xff) << 8) | ((a0[2] & 0xff) << 16) | ((a0[3] & 0xff) << 24);
            o[1] = (a1[0] & 0xff) | ((a1[1] & 0xff) << 8) | ((a1[2] & 0xff) << 16) | ((a1[3] & 0xff) << 24);
            o[2] = (a2[0] & 0xff) | ((a2[1] & 0xff) << 8) | ((a2[2] & 0xff) << 16) | ((a2[3] & 0xff) << 24);
            o[3] = (a3[0] & 0xff) | ((a3[1] & 0xff) << 8) | ((a3[2] & 0xff) << 16) | ((a3[3] & 0xff) << 24);
            reinterpret_cast<int32x4*>(w8)[c] = o;
        }
    } else {
        const int32x4* src = reinterpret_cast<const int32x4*>(w);
        int32x4* dst = reinterpret_cast<int32x4*>(w8);
        for (int c = t; c < chunks; c += nth) dst[c] = src[c];
    }
}

// ---------------------------------------------------------------------------
// Kernel 1: per-row absmax quantization. One block (256 thr) per row, K=4096.
// ---------------------------------------------------------------------------
__global__ __launch_bounds__(256) void quant_rows(
    const float* __restrict__ x, signed char* __restrict__ q,
    float* __restrict__ scale, int K)
{
    const int row = blockIdx.x;
    const int t = threadIdx.x;
    const float4* xr = reinterpret_cast<const float4*>(x + (size_t)row * K);

    float4 v[4];
    float m = 0.f;
#pragma unroll
    for (int i = 0; i < 4; ++i) {
        v[i] = xr[t + i * 256];
        m = fmaxf(m, fmaxf(fmaxf(fabsf(v[i].x), fabsf(v[i].y)),
                           fmaxf(fabsf(v[i].z), fabsf(v[i].w))));
    }
#pragma unroll
    for (int off = 32; off >= 1; off >>= 1)
        m = fmaxf(m, __shfl_xor(m, off, 64));
    __shared__ float wmax[4];
    const int wave = t >> 6;
    if ((t & 63) == 0) wmax[wave] = m;
    __syncthreads();
    m = fmaxf(fmaxf(wmax[0], wmax[1]), fmaxf(wmax[2], wmax[3]));

    const float s   = m / QMAXF;
    const float inv = (m > 0.f) ? (QMAXF / m) : 0.f;
    if (t == 0) scale[row] = s;

    int* qr = reinterpret_cast<int*>(q + (size_t)row * K);
#pragma unroll
    for (int i = 0; i < 4; ++i) {
        const float* f = reinterpret_cast<const float*>(&v[i]);
        unsigned int packed = 0;
#pragma unroll
        for (int j = 0; j < 4; ++j) {
            int qi = __float2int_rn(f[j] * inv);
            qi = qi > 127 ? 127 : (qi < -127 ? -127 : qi);
            packed |= ((unsigned int)(qi & 0xff)) << (8 * j);
        }
        qr[t + i * 256] = (int)packed;
    }
}

// ---------------------------------------------------------------------------
// Kernel 2: int8 GEMM, 256x256 tile, 8 waves (2Mx4N), K-step = 64 bytes,
// 4-buffer LDS, AITER-shape K-loop: ONE barrier per tile, ds_reads of tile
// t+1 (into the alternate register set, no consumer this iter) OVERLAP the
// 32-MFMA cluster of tile t.  Rounds 4/5/7 proved any schedule that issues
// and lgkm0-waits a tile's reads inside the window that consumes them
// serializes LDS and MFMA (3 schedules, identical 170 us).
//
// Per steady iter t:
//   stage(t+3)            4 x global_load_lds  (counted-vmcnt ledger, T4)
//   ldFrags(t+1) -> next  12 x ds_read_b128    (consumed NEXT iter ->
//                                               execute during MFMAs below)
//   mfmaAll(cur)          32 MFMA, register-only (setprio, T5)
//   vmcnt(4)              tile t+2 complete (t+3 stays in flight)
//   lgkmcnt(0)            own reads drained (had the whole MFMA cluster;
//                         protects WAR: next iter's stage rewrites a buffer
//                         whose readers are now provably done)
//   fenced barrier        promotes both waits to all-waves; sched_barrier
//                         fences stop compiler motion across it (round-6 fix)
//
// Ledger: stage-ahead-3, 4 loads/wave/tile. After iter t's VM4: incomplete
// subset of {t+3} -> tiles t+1, t+2 complete -> iter t+1 may ds_read buf
// (t+2)&3. Prologue: stage 0,1,2; VM4 -> tiles 0,1 complete. Tails: VM4 at
// t=NT-4 (NT-2 complete), VM0 at t=NT-3 (NT-1 complete), then no more DMA.
//
// Fragment-order LDS (zero bank conflicts): 1 KB frag-tile fi holds the MFMA
// operand for rows [fi*16,fi*16+16) x 64 k-bytes, lane-linear; per-lane
// global address is row fi*16+(l&15), kcol (l>>4)*16, so every ds_read_b128
// at base + lane*16 is fully linear.
// ---------------------------------------------------------------------------
#define BM 256
#define BN 256
#define BKB 64
#define NBUF 4

__device__ __forceinline__ void async_copy16(const void* g, void* lds) {
    __builtin_amdgcn_global_load_lds(
        (const __attribute__((address_space(1))) void*)g,
        (__attribute__((address_space(3))) void*)lds, 16, 0, 0);
}

// fenced barrier: no memory op may move across, in either direction
#define BARF do {                                         \
    __builtin_amdgcn_sched_barrier(0);                    \
    asm volatile("" ::: "memory");                        \
    __builtin_amdgcn_s_barrier();                         \
    asm volatile("" ::: "memory");                        \
    __builtin_amdgcn_sched_barrier(0);                    \
} while (0)

#define LGKM0 asm volatile("s_waitcnt lgkmcnt(0)" ::: "memory")
#define VM4   asm volatile("s_waitcnt vmcnt(4)" ::: "memory")
#define VM0   asm volatile("s_waitcnt vmcnt(0)" ::: "memory")

__global__ __launch_bounds__(512, 2) void gemm_i8_dequant_ov(
    const signed char* __restrict__ A,   // [M,K] qinp
    const signed char* __restrict__ B,   // [N,K] qweight (packed int8)
    const float* __restrict__ a_scale,   // [M]
    const float* __restrict__ wparams,   // [N]
    const float* __restrict__ bias,      // [N]
    float* __restrict__ out,             // [M,N]
    int M, int N, int K)
{
    __shared__ __align__(16) signed char lds[NBUF * 32768];   // 128 KiB

    const int t    = threadIdx.x;
    const int lane = t & 63;
    const int wave = t >> 6;           // 0..7
    const int wr   = wave >> 2;        // 0..1 (M half)
    const int wc   = wave & 3;         // 0..3 (N quarter)

    // T1: XCD-aware bijective swizzle (nwg % 8 == 0)
    const int nwg = gridDim.x;
    const int cpx = nwg >> 3;
    const int swz = (blockIdx.x & 7) * cpx + (blockIdx.x >> 3);
    const int nbx = N / BN;
    const int rowBase = (swz / nbx) * BM;
    const int colBase = (swz % nbx) * BN;

    const int r15 = lane & 15;
    const int ksl = lane >> 4;

    int32x4 acc[8][4] = {};
    const int NT = K / BKB;            // 64 (even)

    const signed char* gA0 = A + (size_t)(rowBase + wave * 16 + r15)       * K + ksl * 16;
    const signed char* gA1 = A + (size_t)(rowBase + (8 + wave) * 16 + r15) * K + ksl * 16;
    const signed char* gB0 = B + (size_t)(colBase + wave * 16 + r15)       * K + ksl * 16;
    const signed char* gB1 = B + (size_t)(colBase + (8 + wave) * 16 + r15) * K + ksl * 16;

    auto stage = [&](int tile) {
        signed char* L = lds + (tile & (NBUF - 1)) * 32768;
        const size_t kt = (size_t)tile * BKB;
        async_copy16(gA0 + kt, L + wave * 1024);
        async_copy16(gA1 + kt, L + (8 + wave) * 1024);
        async_copy16(gB0 + kt, L + 16384 + wave * 1024);
        async_copy16(gB1 + kt, L + 16384 + (8 + wave) * 1024);
    };
    auto ldFrags = [&](int tile, int32x4 (&fa)[8], int32x4 (&fb)[4]) {
        const signed char* Ab = lds + (tile & (NBUF - 1)) * 32768 + wr * 8192 + lane * 16;
        const signed char* Bb = lds + (tile & (NBUF - 1)) * 32768 + 16384 + wc * 4096 + lane * 16;
#pragma unroll
        for (int mm = 0; mm < 8; ++mm)
            fa[mm] = *reinterpret_cast<const int32x4*>(Ab + mm * 1024);
#pragma unroll
        for (int nn = 0; nn < 4; ++nn)
            fb[nn] = *reinterpret_cast<const int32x4*>(Bb + nn * 1024);
    };
    auto mfmaAll = [&](const int32x4 (&fa)[8], const int32x4 (&fb)[4]) {
        __builtin_amdgcn_s_setprio(1);
#pragma unroll
        for (int mm = 0; mm < 8; ++mm)
#pragma unroll
            for (int nn = 0; nn < 4; ++nn)
                acc[mm][nn] = __builtin_amdgcn_mfma_i32_16x16x64_i8(
                    fa[mm], fb[nn], acc[mm][nn], 0, 0, 0);
        __builtin_amdgcn_s_setprio(0);
    };

    int32x4 cA[8], cB[4], nA[8], nB[4];

    // ---- prologue: stage tiles 0,1,2; tiles 0,1 proven complete ----
    stage(0); stage(1); stage(2);
    VM4;                               // incomplete <= 4 -> tiles 0,1 landed
    BARF;
    ldFrags(0, cA, cB);

    // ---- steady: pairs t = 0,2,..,NT-6 (stages 3..NT-3) ----
    for (int tt = 0; tt + 1 < NT - 3; tt += 2) {
        stage(tt + 3);
        ldFrags(tt + 1, nA, nB);       // executes during mfmaAll below
        mfmaAll(cA, cB);
        VM4; LGKM0; BARF;

        stage(tt + 4);
        ldFrags(tt + 2, cA, cB);
        mfmaAll(nA, nB);
        VM4; LGKM0; BARF;
    }

    // ---- tails: t = NT-4 .. NT-1 (NT even: NT-4 uses cA) ----
    stage(NT - 1);                     // last stage
    ldFrags(NT - 3, nA, nB);
    mfmaAll(cA, cB);
    VM4; LGKM0; BARF;                  // NT-2 complete

    ldFrags(NT - 2, cA, cB);
    mfmaAll(nA, nB);
    VM0; LGKM0; BARF;                  // NT-1 complete

    ldFrags(NT - 1, nA, nB);
    mfmaAll(cA, cB);

    mfmaAll(nA, nB);                   // compiler waits lgkm before use

    // ---- epilogue: dequant + bias. C/D map: col=lane&15, row=(lane>>4)*4+r
#pragma unroll
    for (int mm = 0; mm < 8; ++mm) {
        const int rb = rowBase + wr * 128 + mm * 16 + ksl * 4;
        float asc[4];
#pragma unroll
        for (int r = 0; r < 4; ++r) asc[r] = a_scale[rb + r];
#pragma unroll
        for (int nn = 0; nn < 4; ++nn) {
            const int col = colBase + wc * 64 + nn * 16 + r15;
            const float wp = wparams[col];
            const float bs = bias[col];
#pragma unroll
            for (int r = 0; r < 4; ++r) {
                out[(size_t)(rb + r) * N + col] =
                    (float)acc[mm][nn][r] * asc[r] * wp + bs;
            }
        }
    }
}

// ---------------------------------------------------------------------------
extern "C" void kernel_launch(void* const* d_in, const int* in_sizes, int n_in,
                              void* d_out, int out_size, void* d_ws, size_t ws_size,
                              hipStream_t stream) {
    const float* inp     = (const float*)d_in[0];
    const int*   qw_raw  = (const int*)d_in[1];
    const float* wparams = (const float*)d_in[2];
    const float* bias    = (const float*)d_in[3];
    float*       out     = (float*)d_out;

    const int N = in_sizes[2];             // 4096
    const int K = in_sizes[1] / N;         // 4096
    const int M = in_sizes[0] / K;         // 8192

    // workspace: qinp [M*K B] | a_scale [M*4 B, 256-pad] | w8 [N*K B]
    signed char* qinp    = (signed char*)d_ws;
    float*       a_scale = (float*)((char*)d_ws + (size_t)M * K);
    size_t off_w8 = (size_t)M * K + (((size_t)M * sizeof(float) + 255) & ~(size_t)255);
    signed char* w8      = (signed char*)((char*)d_ws + off_w8);

    repack_weights<<<2048, 256, 0, stream>>>(qw_raw, w8, N * K);
    quant_rows<<<M, 256, 0, stream>>>(inp, qinp, a_scale, K);

    const int nwg = (M / BM) * (N / BN);   // 32*16 = 512, %8 == 0
    gemm_i8_dequant_ov<<<nwg, 512, 0, stream>>>(
        qinp, w8, a_scale, wparams, bias, out, M, N, K);
}